// Round 6
// baseline (363.647 us; speedup 1.0000x reference)
//
#include <hip/hip_runtime.h>

// VQVAE quantize.  x: [8,64,32,32] fp32, codebook: [8192,64] fp32.
// d_out (fp32, concat): [0,524288) quant_out | [524288] commit_loss |
//                       [524289] codebook_loss | [524290,532482) indices
//
// argmin via bf16x3 emulated-fp32 MFMA GEMM:
//   v = h + m + l (3 bf16, exact to ~2^-27); dot = hh+hm+mh+hl+lh+mm
//   score = dot - 0.5*e2[k]  (argmax score == argmin d2; verified absmax 0)

#define N_PTS   8192
#define K_CODES 8192
#define C_DIM   64
#define HWSZ    1024
#define QOUT_N  524288
#define SPLITS  32            // codes per split = 256

// ---- workspace layout (bytes) ----
#define WS_XS    0            // u16 [3][8][8192][8]  = 3145728
#define WS_CBS   3145728      // u16 [3][8][8192][8]  = 3145728
#define WS_E2H   6291456      // float [8192]         = 32768
#define WS_PACK  6324224      // u64 [32][8192]       = 2097152
#define WS_PART  8421376      // float [512]

typedef __attribute__((ext_vector_type(8))) short short8;
typedef __attribute__((ext_vector_type(4))) float floatx4;

__device__ __forceinline__ unsigned short bf16_rne(float f) {
    unsigned u = __float_as_uint(f);
    return (unsigned short)((u + 0x7FFFu + ((u >> 16) & 1u)) >> 16);
}
__device__ __forceinline__ float bf16_val(unsigned short h) {
    return __uint_as_float(((unsigned)h) << 16);
}
__device__ __forceinline__ void split3(float v, unsigned short& h,
                                       unsigned short& m, unsigned short& l) {
    h = bf16_rne(v);
    float r1 = v - bf16_val(h);
    m = bf16_rne(r1);
    float r2 = r1 - bf16_val(m);
    l = bf16_rne(r2);
}

// ============================================================
// Kernel A: prep (no LDS, all coalesced).
//  blocks 0..31  : cb split + e2h (1 row/thread).
//  blocks 32..95 : x split, block=(b,g), 4 points/thread.
// Plane layout [p][g][n][8]: 16B per (point|code, c-octet) == one
// MFMA fragment k-group.
// ============================================================
__global__ __launch_bounds__(256)
void vq_prep_kernel(const float* __restrict__ x,
                    const float* __restrict__ cb,
                    unsigned short* __restrict__ xS,
                    unsigned short* __restrict__ cbS,
                    float* __restrict__ e2h)
{
    const int bx  = blockIdx.x;
    const int tid = threadIdx.x;

    if (bx < 32) {                           // ---- cb split + e2h ----
        const int k = bx * 256 + tid;
        const float* row = cb + k * C_DIM;
        float s = 0.0f;
        #pragma unroll
        for (int g = 0; g < 8; ++g) {
            float4 a = *(const float4*)(row + g * 8);
            float4 b = *(const float4*)(row + g * 8 + 4);
            float vv[8] = {a.x, a.y, a.z, a.w, b.x, b.y, b.z, b.w};
            unsigned short h8[8], m8[8], l8[8];
            #pragma unroll
            for (int j = 0; j < 8; ++j) {
                s = fmaf(vv[j], vv[j], s);
                split3(vv[j], h8[j], m8[j], l8[j]);
            }
            *(uint4*)(cbS + ((size_t)(0 * 8 + g) * 8192 + k) * 8) = *(const uint4*)h8;
            *(uint4*)(cbS + ((size_t)(1 * 8 + g) * 8192 + k) * 8) = *(const uint4*)m8;
            *(uint4*)(cbS + ((size_t)(2 * 8 + g) * 8192 + k) * 8) = *(const uint4*)l8;
        }
        e2h[k] = 0.5f * s;
    } else {                                 // ---- x split ----
        const int u = bx - 32;               // 0..63
        const int b = u >> 3, g = u & 7;
        const float* xb = x + (size_t)(b * C_DIM + g * 8) * HWSZ;
        float v[4][8];                       // [j][cq]
        #pragma unroll
        for (int cq = 0; cq < 8; ++cq) {
            float4 t4 = *(const float4*)(xb + cq * HWSZ + tid * 4);
            v[0][cq] = t4.x; v[1][cq] = t4.y; v[2][cq] = t4.z; v[3][cq] = t4.w;
        }
        #pragma unroll
        for (int j = 0; j < 4; ++j) {
            unsigned short h8[8], m8[8], l8[8];
            #pragma unroll
            for (int cq = 0; cq < 8; ++cq)
                split3(v[j][cq], h8[cq], m8[cq], l8[cq]);
            const size_t n = (size_t)b * 1024 + tid * 4 + j;
            *(uint4*)(xS + ((size_t)(0 * 8 + g) * 8192 + n) * 8) = *(const uint4*)h8;
            *(uint4*)(xS + ((size_t)(1 * 8 + g) * 8192 + n) * 8) = *(const uint4*)m8;
            *(uint4*)(xS + ((size_t)(2 * 8 + g) * 8192 + n) * 8) = *(const uint4*)l8;
        }
    }
}

// ============================================================
// Kernel B: argmin via MFMA. grid (32 m-blocks, 32 splits) = 1024
// blocks = 4 blocks/CU (VGPR<=128, LDS 34.8KB -> occupancy 4).
// Wave owns 64 points (4 tiles of 16); A-frags in regs (96 VGPR).
// 16 N-tiles of 16 codes, unrolled x2 with reg double-buffer.
// acc init = -0.5*e2 (C-operand), track max of dot-0.5*e2.
// Layouts (verified m89/m91/m120): A[m=lane&15][k=quad*8+j],
// B[k=quad*8+j][n=lane&15], C: col=lane&15, row=quad*4+reg.
// ============================================================
__device__ __forceinline__ void loadB(const unsigned short* __restrict__ cbS,
                                      const float* __restrict__ e2h,
                                      int code, int quad,
                                      short8 bf[3][2], float& me2)
{
    #pragma unroll
    for (int p = 0; p < 3; ++p)
        #pragma unroll
        for (int s = 0; s < 2; ++s) {
            int g = s * 4 + quad;
            bf[p][s] = *(const short8*)(cbS + ((size_t)(p * 8 + g) * 8192 + code) * 8);
        }
    me2 = -e2h[code];
}

__device__ __forceinline__ void computeTile(const short8 af[4][3][2],
                                            const short8 bf[3][2],
                                            float me2, int code,
                                            float bestv[4][4], int besti[4][4])
{
    floatx4 acc[4];
    #pragma unroll
    for (int t = 0; t < 4; ++t) acc[t] = (floatx4){me2, me2, me2, me2};

    #pragma unroll
    for (int s = 0; s < 2; ++s) {
        #pragma unroll
        for (int t = 0; t < 4; ++t)
            acc[t] = __builtin_amdgcn_mfma_f32_16x16x32_bf16(af[t][0][s], bf[0][s], acc[t], 0, 0, 0); // hh
        #pragma unroll
        for (int t = 0; t < 4; ++t)
            acc[t] = __builtin_amdgcn_mfma_f32_16x16x32_bf16(af[t][0][s], bf[1][s], acc[t], 0, 0, 0); // hm
        #pragma unroll
        for (int t = 0; t < 4; ++t)
            acc[t] = __builtin_amdgcn_mfma_f32_16x16x32_bf16(af[t][1][s], bf[0][s], acc[t], 0, 0, 0); // mh
        #pragma unroll
        for (int t = 0; t < 4; ++t)
            acc[t] = __builtin_amdgcn_mfma_f32_16x16x32_bf16(af[t][0][s], bf[2][s], acc[t], 0, 0, 0); // hl
        #pragma unroll
        for (int t = 0; t < 4; ++t)
            acc[t] = __builtin_amdgcn_mfma_f32_16x16x32_bf16(af[t][2][s], bf[0][s], acc[t], 0, 0, 0); // lh
        #pragma unroll
        for (int t = 0; t < 4; ++t)
            acc[t] = __builtin_amdgcn_mfma_f32_16x16x32_bf16(af[t][1][s], bf[1][s], acc[t], 0, 0, 0); // mm
    }

    #pragma unroll
    for (int t = 0; t < 4; ++t)
        #pragma unroll
        for (int r = 0; r < 4; ++r) {
            float sc = acc[t][r];
            bool gt = sc > bestv[t][r];        // strict: earlier code wins ties
            bestv[t][r] = gt ? sc   : bestv[t][r];
            besti[t][r] = gt ? code : besti[t][r];
        }
}

__global__ __launch_bounds__(256, 4)
void vq_argmin_kernel(const unsigned short* __restrict__ xS,
                      const unsigned short* __restrict__ cbS,
                      const float* __restrict__ e2h,
                      unsigned long long* __restrict__ packedS)
{
    __shared__ unsigned long long red[256][17];
    const int tid   = threadIdx.x;
    const int lane  = tid & 63;
    const int w     = tid >> 6;
    const int col   = lane & 15;
    const int quad  = lane >> 4;
    const int mb    = blockIdx.x;
    const int split = blockIdx.y;
    const int m0    = mb * 256 + w * 64;
    const int nb0   = split * 256;

    // A fragments: 4 tiles x 3 planes x 2 ksteps (96 VGPRs)
    short8 af[4][3][2];
    #pragma unroll
    for (int t = 0; t < 4; ++t) {
        int pt = m0 + t * 16 + col;
        #pragma unroll
        for (int p = 0; p < 3; ++p)
            #pragma unroll
            for (int s = 0; s < 2; ++s) {
                int g = s * 4 + quad;
                af[t][p][s] = *(const short8*)(xS + ((size_t)(p * 8 + g) * 8192 + pt) * 8);
            }
    }

    float bestv[4][4];
    int   besti[4][4];
    #pragma unroll
    for (int t = 0; t < 4; ++t)
        #pragma unroll
        for (int r = 0; r < 4; ++r) {
            bestv[t][r] = __uint_as_float(0xFF800000u);  // -inf
            besti[t][r] = 0;
        }

    short8 b0[3][2], b1[3][2];
    float  e0, e1;
    loadB(cbS, e2h, nb0 + col, quad, b0, e0);

    for (int nt = 0; nt < 16; nt += 2) {
        loadB(cbS, e2h, nb0 + (nt + 1) * 16 + col, quad, b1, e1);
        computeTile(af, b0, e0, nb0 + nt * 16 + col, bestv, besti);
        if (nt + 2 < 16)
            loadB(cbS, e2h, nb0 + (nt + 2) * 16 + col, quad, b0, e0);
        computeTile(af, b1, e1, nb0 + (nt + 1) * 16 + col, bestv, besti);
    }

    // pack (key = -score, ascending) + cross-col reduce via LDS
    #pragma unroll
    for (int t = 0; t < 4; ++t)
        #pragma unroll
        for (int r = 0; r < 4; ++r) {
            unsigned u = __float_as_uint(-bestv[t][r]);
            u = ((int)u < 0) ? ~u : (u | 0x80000000u);
            unsigned long long p = ((unsigned long long)u << 32) | (unsigned)besti[t][r];
            red[w * 64 + t * 16 + quad * 4 + r][col] = p;
        }
    __syncthreads();
    unsigned long long v = red[tid][0];
    #pragma unroll
    for (int c = 1; c < 16; ++c) {
        unsigned long long q = red[tid][c];
        v = (q < v) ? q : v;
    }
    packedS[(size_t)split * N_PTS + mb * 256 + tid] = v;
}

// ============================================================
// Kernel C: gather. 128 blocks x 256; block owns 64 points.
// Wave 0 reduces the 32 split slots once per point, broadcasts
// idx via LDS + writes indices. All 4 waves then handle one
// 16-channel quarter each (fully coalesced x/out access).
// ============================================================
__global__ __launch_bounds__(256)
void vq_gather_kernel(const float* __restrict__ x,
                      const float* __restrict__ cb,
                      const unsigned long long* __restrict__ packedS,
                      float* __restrict__ out,
                      float* __restrict__ part)
{
    __shared__ int sidx[64];
    const int tid  = threadIdx.x;
    const int lane = tid & 63;
    const int qd   = tid >> 6;          // wave id = channel quarter
    const int n0   = blockIdx.x * 64;
    const int n    = n0 + lane;

    if (qd == 0) {
        unsigned long long v = packedS[n];
        #pragma unroll
        for (int s = 1; s < SPLITS; ++s) {
            unsigned long long q = packedS[(size_t)s * N_PTS + n];
            v = (q < v) ? q : v;
        }
        int idx = (int)(v & 0xFFFFFFFFull);
        sidx[lane] = idx;
        out[QOUT_N + 2 + n] = (float)idx;
    }
    __syncthreads();

    const int idx = sidx[lane];
    const int c0  = qd * 16;
    const int b   = n >> 10;
    const int hw  = n & 1023;
    const float* xb = x   + (size_t)b * (C_DIM * HWSZ) + hw;
    float*       ob = out + (size_t)b * (C_DIM * HWSZ) + hw;

    float s = 0.0f;
    #pragma unroll
    for (int c4 = 0; c4 < 4; ++c4) {
        float4 q = *(const float4*)(cb + (size_t)idx * C_DIM + c0 + c4 * 4);
        float qa[4] = {q.x, q.y, q.z, q.w};
        #pragma unroll
        for (int j = 0; j < 4; ++j) {
            int c = c0 + c4 * 4 + j;
            float xv = xb[c * HWSZ];
            float d  = qa[j] - xv;          // quant - x (reference rounding)
            s = fmaf(d, d, s);
            ob[c * HWSZ] = xv + d;          // straight-through: x + (q - x)
        }
    }

    #pragma unroll
    for (int off = 32; off > 0; off >>= 1) s += __shfl_down(s, off, 64);
    if (lane == 0) part[blockIdx.x * 4 + qd] = s;
}

// ============================================================
// Kernel D: final loss reduction (512 partials -> 2 scalars).
// ============================================================
__global__ __launch_bounds__(256)
void vq_final_kernel(const float* __restrict__ part, float* __restrict__ out)
{
    __shared__ float w[4];
    float s = part[threadIdx.x] + part[threadIdx.x + 256];
    #pragma unroll
    for (int off = 32; off > 0; off >>= 1) s += __shfl_down(s, off, 64);
    if ((threadIdx.x & 63) == 0) w[threadIdx.x >> 6] = s;
    __syncthreads();
    if (threadIdx.x == 0) {
        float m = (w[0] + w[1] + w[2] + w[3]) * (1.0f / (float)QOUT_N);
        out[QOUT_N]     = m;   // commitment_loss
        out[QOUT_N + 1] = m;   // codebook_loss
    }
}

extern "C" void kernel_launch(void* const* d_in, const int* in_sizes, int n_in,
                              void* d_out, int out_size, void* d_ws, size_t ws_size,
                              hipStream_t stream)
{
    const float* x  = (const float*)d_in[0];   // [8,64,32,32]
    const float* cb = (const float*)d_in[1];   // [8192,64]
    float* out = (float*)d_out;
    char*  ws  = (char*)d_ws;
    (void)ws_size;

    unsigned short* xS  = (unsigned short*)(ws + WS_XS);
    unsigned short* cbS = (unsigned short*)(ws + WS_CBS);
    float* e2h = (float*)(ws + WS_E2H);
    unsigned long long* packedS = (unsigned long long*)(ws + WS_PACK);
    float* part = (float*)(ws + WS_PART);

    vq_prep_kernel<<<96, 256, 0, stream>>>(x, cb, xS, cbS, e2h);
    vq_argmin_kernel<<<dim3(N_PTS / 256, SPLITS), 256, 0, stream>>>(xS, cbS, e2h, packedS);
    vq_gather_kernel<<<128, 256, 0, stream>>>(x, cb, packedS, out, part);
    vq_final_kernel<<<1, 256, 0, stream>>>(part, out);
}

// Round 7
// 107.668 us; speedup vs baseline: 3.3775x; 3.3775x over previous
//
#include <hip/hip_runtime.h>

// VQVAE quantize.  x: [8,64,32,32] fp32, codebook: [8192,64] fp32.
// d_out (fp32, concat): [0,524288) quant_out | [524288] commit_loss |
//                       [524289] codebook_loss | [524290,532482) indices
//
// argmin via bf16x3 emulated-fp32 MFMA GEMM:
//   v = h + m + l (3 bf16, exact to ~2^-27); dot = hh+hm+mh+hl+lh+mm
//   score = dot - 0.5*e2[k]  (argmax score == argmin d2; verified absmax 0)
//
// R6 lesson: do NOT tighten __launch_bounds__ min-waves beyond what the
// natural VGPR allocation (~120 <= 128) already gives — (256,4) forced a
// 64-VGPR allocation and 800+ MB of scratch spill traffic.

#define N_PTS   8192
#define K_CODES 8192
#define C_DIM   64
#define HWSZ    1024
#define QOUT_N  524288
#define SPLITS  32            // codes per split = 256

// ---- workspace layout (bytes) ----
#define WS_XS    0            // u16 [3][8][8192][8]  = 3145728
#define WS_CBS   3145728      // u16 [3][8][8192][8]  = 3145728
#define WS_E2H   6291456      // float [8192]         = 32768
#define WS_PACK  6324224      // u64 [32][8192]       = 2097152
#define WS_PART  8421376      // float [512]

typedef __attribute__((ext_vector_type(8))) short short8;
typedef __attribute__((ext_vector_type(4))) float floatx4;

__device__ __forceinline__ unsigned short bf16_rne(float f) {
    unsigned u = __float_as_uint(f);
    return (unsigned short)((u + 0x7FFFu + ((u >> 16) & 1u)) >> 16);
}
__device__ __forceinline__ float bf16_val(unsigned short h) {
    return __uint_as_float(((unsigned)h) << 16);
}
__device__ __forceinline__ void split3(float v, unsigned short& h,
                                       unsigned short& m, unsigned short& l) {
    h = bf16_rne(v);
    float r1 = v - bf16_val(h);
    m = bf16_rne(r1);
    float r2 = r1 - bf16_val(m);
    l = bf16_rne(r2);
}

// ============================================================
// Kernel A: prep (no LDS, all coalesced).
//  blocks 0..31  : cb split + e2h (1 row/thread).
//  blocks 32..95 : x split, block=(b,g), 4 points/thread.
// Plane layout [p][g][n][8]: 16B per (point|code, c-octet) == one
// MFMA fragment k-group.
// ============================================================
__global__ __launch_bounds__(256)
void vq_prep_kernel(const float* __restrict__ x,
                    const float* __restrict__ cb,
                    unsigned short* __restrict__ xS,
                    unsigned short* __restrict__ cbS,
                    float* __restrict__ e2h)
{
    const int bx  = blockIdx.x;
    const int tid = threadIdx.x;

    if (bx < 32) {                           // ---- cb split + e2h ----
        const int k = bx * 256 + tid;
        const float* row = cb + k * C_DIM;
        float s = 0.0f;
        #pragma unroll
        for (int g = 0; g < 8; ++g) {
            float4 a = *(const float4*)(row + g * 8);
            float4 b = *(const float4*)(row + g * 8 + 4);
            float vv[8] = {a.x, a.y, a.z, a.w, b.x, b.y, b.z, b.w};
            unsigned short h8[8], m8[8], l8[8];
            #pragma unroll
            for (int j = 0; j < 8; ++j) {
                s = fmaf(vv[j], vv[j], s);
                split3(vv[j], h8[j], m8[j], l8[j]);
            }
            *(uint4*)(cbS + ((size_t)(0 * 8 + g) * 8192 + k) * 8) = *(const uint4*)h8;
            *(uint4*)(cbS + ((size_t)(1 * 8 + g) * 8192 + k) * 8) = *(const uint4*)m8;
            *(uint4*)(cbS + ((size_t)(2 * 8 + g) * 8192 + k) * 8) = *(const uint4*)l8;
        }
        e2h[k] = 0.5f * s;
    } else {                                 // ---- x split ----
        const int u = bx - 32;               // 0..63
        const int b = u >> 3, g = u & 7;
        const float* xb = x + (size_t)(b * C_DIM + g * 8) * HWSZ;
        float v[4][8];                       // [j][cq]
        #pragma unroll
        for (int cq = 0; cq < 8; ++cq) {
            float4 t4 = *(const float4*)(xb + cq * HWSZ + tid * 4);
            v[0][cq] = t4.x; v[1][cq] = t4.y; v[2][cq] = t4.z; v[3][cq] = t4.w;
        }
        #pragma unroll
        for (int j = 0; j < 4; ++j) {
            unsigned short h8[8], m8[8], l8[8];
            #pragma unroll
            for (int cq = 0; cq < 8; ++cq)
                split3(v[j][cq], h8[cq], m8[cq], l8[cq]);
            const size_t n = (size_t)b * 1024 + tid * 4 + j;
            *(uint4*)(xS + ((size_t)(0 * 8 + g) * 8192 + n) * 8) = *(const uint4*)h8;
            *(uint4*)(xS + ((size_t)(1 * 8 + g) * 8192 + n) * 8) = *(const uint4*)m8;
            *(uint4*)(xS + ((size_t)(2 * 8 + g) * 8192 + n) * 8) = *(const uint4*)l8;
        }
    }
}

// ============================================================
// Kernel B: argmin via MFMA. grid (32 m-blocks, 32 splits) = 1024
// blocks; natural VGPR ~120 <= 128 -> 4 blocks/CU without forcing.
// Wave owns 64 points (4 tiles of 16); A-frags in regs (96 VGPR).
// 16 N-tiles of 16 codes, unrolled x2 with reg double-buffer.
// acc init = -0.5*e2 (C-operand), track max of dot-0.5*e2.
// Layouts (verified m89/m91/m120): A[m=lane&15][k=quad*8+j],
// B[k=quad*8+j][n=lane&15], C: col=lane&15, row=quad*4+reg.
// ============================================================
__device__ __forceinline__ void loadB(const unsigned short* __restrict__ cbS,
                                      const float* __restrict__ e2h,
                                      int code, int quad,
                                      short8 bf[3][2], float& me2)
{
    #pragma unroll
    for (int p = 0; p < 3; ++p)
        #pragma unroll
        for (int s = 0; s < 2; ++s) {
            int g = s * 4 + quad;
            bf[p][s] = *(const short8*)(cbS + ((size_t)(p * 8 + g) * 8192 + code) * 8);
        }
    me2 = -e2h[code];
}

__device__ __forceinline__ void computeTile(const short8 af[4][3][2],
                                            const short8 bf[3][2],
                                            float me2, int code,
                                            float bestv[4][4], int besti[4][4])
{
    floatx4 acc[4];
    #pragma unroll
    for (int t = 0; t < 4; ++t) acc[t] = (floatx4){me2, me2, me2, me2};

    #pragma unroll
    for (int s = 0; s < 2; ++s) {
        #pragma unroll
        for (int t = 0; t < 4; ++t)
            acc[t] = __builtin_amdgcn_mfma_f32_16x16x32_bf16(af[t][0][s], bf[0][s], acc[t], 0, 0, 0); // hh
        #pragma unroll
        for (int t = 0; t < 4; ++t)
            acc[t] = __builtin_amdgcn_mfma_f32_16x16x32_bf16(af[t][0][s], bf[1][s], acc[t], 0, 0, 0); // hm
        #pragma unroll
        for (int t = 0; t < 4; ++t)
            acc[t] = __builtin_amdgcn_mfma_f32_16x16x32_bf16(af[t][1][s], bf[0][s], acc[t], 0, 0, 0); // mh
        #pragma unroll
        for (int t = 0; t < 4; ++t)
            acc[t] = __builtin_amdgcn_mfma_f32_16x16x32_bf16(af[t][0][s], bf[2][s], acc[t], 0, 0, 0); // hl
        #pragma unroll
        for (int t = 0; t < 4; ++t)
            acc[t] = __builtin_amdgcn_mfma_f32_16x16x32_bf16(af[t][2][s], bf[0][s], acc[t], 0, 0, 0); // lh
        #pragma unroll
        for (int t = 0; t < 4; ++t)
            acc[t] = __builtin_amdgcn_mfma_f32_16x16x32_bf16(af[t][1][s], bf[1][s], acc[t], 0, 0, 0); // mm
    }

    #pragma unroll
    for (int t = 0; t < 4; ++t)
        #pragma unroll
        for (int r = 0; r < 4; ++r) {
            float sc = acc[t][r];
            bool gt = sc > bestv[t][r];        // strict: earlier code wins ties
            bestv[t][r] = gt ? sc   : bestv[t][r];
            besti[t][r] = gt ? code : besti[t][r];
        }
}

__global__ __launch_bounds__(256, 2)
void vq_argmin_kernel(const unsigned short* __restrict__ xS,
                      const unsigned short* __restrict__ cbS,
                      const float* __restrict__ e2h,
                      unsigned long long* __restrict__ packedS)
{
    __shared__ unsigned long long red[256][17];
    const int tid   = threadIdx.x;
    const int lane  = tid & 63;
    const int w     = tid >> 6;
    const int col   = lane & 15;
    const int quad  = lane >> 4;
    const int mb    = blockIdx.x;
    const int split = blockIdx.y;
    const int m0    = mb * 256 + w * 64;
    const int nb0   = split * 256;

    // A fragments: 4 tiles x 3 planes x 2 ksteps (96 VGPRs)
    short8 af[4][3][2];
    #pragma unroll
    for (int t = 0; t < 4; ++t) {
        int pt = m0 + t * 16 + col;
        #pragma unroll
        for (int p = 0; p < 3; ++p)
            #pragma unroll
            for (int s = 0; s < 2; ++s) {
                int g = s * 4 + quad;
                af[t][p][s] = *(const short8*)(xS + ((size_t)(p * 8 + g) * 8192 + pt) * 8);
            }
    }

    float bestv[4][4];
    int   besti[4][4];
    #pragma unroll
    for (int t = 0; t < 4; ++t)
        #pragma unroll
        for (int r = 0; r < 4; ++r) {
            bestv[t][r] = __uint_as_float(0xFF800000u);  // -inf
            besti[t][r] = 0;
        }

    short8 b0[3][2], b1[3][2];
    float  e0, e1;
    loadB(cbS, e2h, nb0 + col, quad, b0, e0);

    for (int nt = 0; nt < 16; nt += 2) {
        loadB(cbS, e2h, nb0 + (nt + 1) * 16 + col, quad, b1, e1);
        computeTile(af, b0, e0, nb0 + nt * 16 + col, bestv, besti);
        if (nt + 2 < 16)
            loadB(cbS, e2h, nb0 + (nt + 2) * 16 + col, quad, b0, e0);
        computeTile(af, b1, e1, nb0 + (nt + 1) * 16 + col, bestv, besti);
    }

    // pack (key = -score, ascending) + cross-col reduce via LDS
    #pragma unroll
    for (int t = 0; t < 4; ++t)
        #pragma unroll
        for (int r = 0; r < 4; ++r) {
            unsigned u = __float_as_uint(-bestv[t][r]);
            u = ((int)u < 0) ? ~u : (u | 0x80000000u);
            unsigned long long p = ((unsigned long long)u << 32) | (unsigned)besti[t][r];
            red[w * 64 + t * 16 + quad * 4 + r][col] = p;
        }
    __syncthreads();
    unsigned long long v = red[tid][0];
    #pragma unroll
    for (int c = 1; c < 16; ++c) {
        unsigned long long q = red[tid][c];
        v = (q < v) ? q : v;
    }
    packedS[(size_t)split * N_PTS + mb * 256 + tid] = v;
}

// ============================================================
// Kernel C: gather. 128 blocks x 256; block owns 64 points.
// Wave 0 reduces the 32 split slots once per point, broadcasts
// idx via LDS + writes indices. All 4 waves then handle one
// 16-channel quarter each (fully coalesced x/out access).
// ============================================================
__global__ __launch_bounds__(256)
void vq_gather_kernel(const float* __restrict__ x,
                      const float* __restrict__ cb,
                      const unsigned long long* __restrict__ packedS,
                      float* __restrict__ out,
                      float* __restrict__ part)
{
    __shared__ int sidx[64];
    const int tid  = threadIdx.x;
    const int lane = tid & 63;
    const int qd   = tid >> 6;          // wave id = channel quarter
    const int n0   = blockIdx.x * 64;
    const int n    = n0 + lane;

    if (qd == 0) {
        unsigned long long v = packedS[n];
        #pragma unroll
        for (int s = 1; s < SPLITS; ++s) {
            unsigned long long q = packedS[(size_t)s * N_PTS + n];
            v = (q < v) ? q : v;
        }
        int idx = (int)(v & 0xFFFFFFFFull);
        sidx[lane] = idx;
        out[QOUT_N + 2 + n] = (float)idx;
    }
    __syncthreads();

    const int idx = sidx[lane];
    const int c0  = qd * 16;
    const int b   = n >> 10;
    const int hw  = n & 1023;
    const float* xb = x   + (size_t)b * (C_DIM * HWSZ) + hw;
    float*       ob = out + (size_t)b * (C_DIM * HWSZ) + hw;

    float s = 0.0f;
    #pragma unroll
    for (int c4 = 0; c4 < 4; ++c4) {
        float4 q = *(const float4*)(cb + (size_t)idx * C_DIM + c0 + c4 * 4);
        float qa[4] = {q.x, q.y, q.z, q.w};
        #pragma unroll
        for (int j = 0; j < 4; ++j) {
            int c = c0 + c4 * 4 + j;
            float xv = xb[c * HWSZ];
            float d  = qa[j] - xv;          // quant - x (reference rounding)
            s = fmaf(d, d, s);
            ob[c * HWSZ] = xv + d;          // straight-through: x + (q - x)
        }
    }

    #pragma unroll
    for (int off = 32; off > 0; off >>= 1) s += __shfl_down(s, off, 64);
    if (lane == 0) part[blockIdx.x * 4 + qd] = s;
}

// ============================================================
// Kernel D: final loss reduction (512 partials -> 2 scalars).
// ============================================================
__global__ __launch_bounds__(256)
void vq_final_kernel(const float* __restrict__ part, float* __restrict__ out)
{
    __shared__ float w[4];
    float s = part[threadIdx.x] + part[threadIdx.x + 256];
    #pragma unroll
    for (int off = 32; off > 0; off >>= 1) s += __shfl_down(s, off, 64);
    if ((threadIdx.x & 63) == 0) w[threadIdx.x >> 6] = s;
    __syncthreads();
    if (threadIdx.x == 0) {
        float m = (w[0] + w[1] + w[2] + w[3]) * (1.0f / (float)QOUT_N);
        out[QOUT_N]     = m;   // commitment_loss
        out[QOUT_N + 1] = m;   // codebook_loss
    }
}

extern "C" void kernel_launch(void* const* d_in, const int* in_sizes, int n_in,
                              void* d_out, int out_size, void* d_ws, size_t ws_size,
                              hipStream_t stream)
{
    const float* x  = (const float*)d_in[0];   // [8,64,32,32]
    const float* cb = (const float*)d_in[1];   // [8192,64]
    float* out = (float*)d_out;
    char*  ws  = (char*)d_ws;
    (void)ws_size;

    unsigned short* xS  = (unsigned short*)(ws + WS_XS);
    unsigned short* cbS = (unsigned short*)(ws + WS_CBS);
    float* e2h = (float*)(ws + WS_E2H);
    unsigned long long* packedS = (unsigned long long*)(ws + WS_PACK);
    float* part = (float*)(ws + WS_PART);

    vq_prep_kernel<<<96, 256, 0, stream>>>(x, cb, xS, cbS, e2h);
    vq_argmin_kernel<<<dim3(N_PTS / 256, SPLITS), 256, 0, stream>>>(xS, cbS, e2h, packedS);
    vq_gather_kernel<<<128, 256, 0, stream>>>(x, cb, packedS, out, part);
    vq_final_kernel<<<1, 256, 0, stream>>>(part, out);
}

// Round 8
// 103.817 us; speedup vs baseline: 3.5028x; 1.0371x over previous
//
#include <hip/hip_runtime.h>

// VQVAE quantize.  x: [8,64,32,32] fp32, codebook: [8192,64] fp32.
// d_out (fp32, concat): [0,524288) quant_out | [524288] commit_loss |
//                       [524289] codebook_loss | [524290,532482) indices
//
// argmin via bf16x3 emulated-fp32 MFMA GEMM:
//   v = h + m + l (3 bf16, exact to ~2^-27); dot = hh+hm+mh+hl+lh+mm
//   score = dot - 0.5*e2[k]  (argmax score == argmin d2; verified absmax 0)
//
// R7 lesson: per-wave B-frag loads saturate the L2 request rate (~3.2M
// line-requests); extra waves don't help. Fix: stage B chunks into LDS
// once per block (global_load_lds, 2-barrier double buffer) -> 4x fewer
// L2 requests; waves read B via ds_read_b128.
// R6 lesson: never tighten __launch_bounds__ below natural VGPR alloc.

#define N_PTS   8192
#define K_CODES 8192
#define C_DIM   64
#define HWSZ    1024
#define QOUT_N  524288
#define SPLITS  32            // codes per split = 256 = 4 chunks of 64

// ---- workspace layout (bytes) ----
#define WS_XS    0            // u16 [3][8][8192][8]  = 3145728
#define WS_CBS   3145728      // u16 [3*8][8192][8]   = 3145728
#define WS_E2H   6291456      // float [8192]         = 32768
#define WS_PACK  6324224      // u64 [32][8192]       = 2097152
#define WS_PART  8421376      // float [512]

typedef __attribute__((ext_vector_type(8))) short short8;
typedef __attribute__((ext_vector_type(4))) float floatx4;

__device__ __forceinline__ unsigned short bf16_rne(float f) {
    unsigned u = __float_as_uint(f);
    return (unsigned short)((u + 0x7FFFu + ((u >> 16) & 1u)) >> 16);
}
__device__ __forceinline__ float bf16_val(unsigned short h) {
    return __uint_as_float(((unsigned)h) << 16);
}
__device__ __forceinline__ void split3(float v, unsigned short& h,
                                       unsigned short& m, unsigned short& l) {
    h = bf16_rne(v);
    float r1 = v - bf16_val(h);
    m = bf16_rne(r1);
    float r2 = r1 - bf16_val(m);
    l = bf16_rne(r2);
}
__device__ __forceinline__ void cp16(const void* g, void* l) {
    __builtin_amdgcn_global_load_lds(
        (const __attribute__((address_space(1))) void*)g,
        (__attribute__((address_space(3))) void*)l, 16, 0, 0);
}
__device__ __forceinline__ void cp4(const void* g, void* l) {
    __builtin_amdgcn_global_load_lds(
        (const __attribute__((address_space(1))) void*)g,
        (__attribute__((address_space(3))) void*)l, 4, 0, 0);
}

// ============================================================
// Kernel A: prep (no LDS, all coalesced).
//  blocks 0..31  : cb split + e2h (1 row/thread).
//  blocks 32..95 : x split, block=(b,g), 4 points/thread.
// Plane layout [p*8+g][n][8]: 16B per (point|code, c-octet) == one
// MFMA fragment k-group.
// ============================================================
__global__ __launch_bounds__(256)
void vq_prep_kernel(const float* __restrict__ x,
                    const float* __restrict__ cb,
                    unsigned short* __restrict__ xS,
                    unsigned short* __restrict__ cbS,
                    float* __restrict__ e2h)
{
    const int bx  = blockIdx.x;
    const int tid = threadIdx.x;

    if (bx < 32) {                           // ---- cb split + e2h ----
        const int k = bx * 256 + tid;
        const float* row = cb + k * C_DIM;
        float s = 0.0f;
        #pragma unroll
        for (int g = 0; g < 8; ++g) {
            float4 a = *(const float4*)(row + g * 8);
            float4 b = *(const float4*)(row + g * 8 + 4);
            float vv[8] = {a.x, a.y, a.z, a.w, b.x, b.y, b.z, b.w};
            unsigned short h8[8], m8[8], l8[8];
            #pragma unroll
            for (int j = 0; j < 8; ++j) {
                s = fmaf(vv[j], vv[j], s);
                split3(vv[j], h8[j], m8[j], l8[j]);
            }
            *(uint4*)(cbS + ((size_t)(0 * 8 + g) * 8192 + k) * 8) = *(const uint4*)h8;
            *(uint4*)(cbS + ((size_t)(1 * 8 + g) * 8192 + k) * 8) = *(const uint4*)m8;
            *(uint4*)(cbS + ((size_t)(2 * 8 + g) * 8192 + k) * 8) = *(const uint4*)l8;
        }
        e2h[k] = 0.5f * s;
    } else {                                 // ---- x split ----
        const int u = bx - 32;               // 0..63
        const int b = u >> 3, g = u & 7;
        const float* xb = x + (size_t)(b * C_DIM + g * 8) * HWSZ;
        float v[4][8];                       // [j][cq]
        #pragma unroll
        for (int cq = 0; cq < 8; ++cq) {
            float4 t4 = *(const float4*)(xb + cq * HWSZ + tid * 4);
            v[0][cq] = t4.x; v[1][cq] = t4.y; v[2][cq] = t4.z; v[3][cq] = t4.w;
        }
        #pragma unroll
        for (int j = 0; j < 4; ++j) {
            unsigned short h8[8], m8[8], l8[8];
            #pragma unroll
            for (int cq = 0; cq < 8; ++cq)
                split3(v[j][cq], h8[cq], m8[cq], l8[cq]);
            const size_t n = (size_t)b * 1024 + tid * 4 + j;
            *(uint4*)(xS + ((size_t)(0 * 8 + g) * 8192 + n) * 8) = *(const uint4*)h8;
            *(uint4*)(xS + ((size_t)(1 * 8 + g) * 8192 + n) * 8) = *(const uint4*)m8;
            *(uint4*)(xS + ((size_t)(2 * 8 + g) * 8192 + n) * 8) = *(const uint4*)l8;
        }
    }
}

// ============================================================
// Kernel B: argmin via MFMA. grid (32 m-blocks, 32 splits).
// Wave owns 64 points (4 tiles of 16); A-frags in regs (96 VGPR).
// B staged per 64-code chunk into LDS (global_load_lds x6/thread +
// e2 slice), double-buffered, m97 2-barrier structure; waves read
// B-frags via ds_read_b128 (quarter-wave 256B contiguous, bank-
// balanced). 4 chunks/split, 4 tiles/chunk.
// Layouts (verified m89/m91/m120): A[m=lane&15][k=quad*8+j],
// B[k=quad*8+j][n=lane&15], C: col=lane&15, row=quad*4+reg.
// ============================================================
#define SEG_SHORTS 512        // 64 codes * 8 shorts per (p,g) segment
#define BUF_SHORTS 12416      // 24 segs * 512 + 128 shorts (e2 slice 64 floats)

__device__ __forceinline__ void computeTileLDS(const short8 af[4][3][2],
                                               const unsigned short* __restrict__ bsrc,
                                               int tl, int quad, int col, int code,
                                               float bestv[4][4], int besti[4][4])
{
    short8 bf[3][2];
    #pragma unroll
    for (int p = 0; p < 3; ++p)
        #pragma unroll
        for (int s = 0; s < 2; ++s) {
            int seg = p * 8 + s * 4 + quad;
            bf[p][s] = *(const short8*)(bsrc + seg * SEG_SHORTS + (tl * 16 + col) * 8);
        }
    float me2 = -((const float*)(bsrc + 24 * SEG_SHORTS))[tl * 16 + col];

    floatx4 acc[4];
    #pragma unroll
    for (int t = 0; t < 4; ++t) acc[t] = (floatx4){me2, me2, me2, me2};

    #pragma unroll
    for (int s = 0; s < 2; ++s) {
        #pragma unroll
        for (int t = 0; t < 4; ++t)
            acc[t] = __builtin_amdgcn_mfma_f32_16x16x32_bf16(af[t][0][s], bf[0][s], acc[t], 0, 0, 0); // hh
        #pragma unroll
        for (int t = 0; t < 4; ++t)
            acc[t] = __builtin_amdgcn_mfma_f32_16x16x32_bf16(af[t][0][s], bf[1][s], acc[t], 0, 0, 0); // hm
        #pragma unroll
        for (int t = 0; t < 4; ++t)
            acc[t] = __builtin_amdgcn_mfma_f32_16x16x32_bf16(af[t][1][s], bf[0][s], acc[t], 0, 0, 0); // mh
        #pragma unroll
        for (int t = 0; t < 4; ++t)
            acc[t] = __builtin_amdgcn_mfma_f32_16x16x32_bf16(af[t][0][s], bf[2][s], acc[t], 0, 0, 0); // hl
        #pragma unroll
        for (int t = 0; t < 4; ++t)
            acc[t] = __builtin_amdgcn_mfma_f32_16x16x32_bf16(af[t][2][s], bf[0][s], acc[t], 0, 0, 0); // lh
        #pragma unroll
        for (int t = 0; t < 4; ++t)
            acc[t] = __builtin_amdgcn_mfma_f32_16x16x32_bf16(af[t][1][s], bf[1][s], acc[t], 0, 0, 0); // mm
    }

    #pragma unroll
    for (int t = 0; t < 4; ++t)
        #pragma unroll
        for (int r = 0; r < 4; ++r) {
            float sc = acc[t][r];
            bool gt = sc > bestv[t][r];        // strict: earlier code wins ties
            bestv[t][r] = gt ? sc   : bestv[t][r];
            besti[t][r] = gt ? code : besti[t][r];
        }
}

__global__ __launch_bounds__(256, 2)
void vq_argmin_kernel(const unsigned short* __restrict__ xS,
                      const unsigned short* __restrict__ cbS,
                      const float* __restrict__ e2h,
                      unsigned long long* __restrict__ packedS)
{
    __shared__ __align__(16) unsigned short sBuf[2][BUF_SHORTS];  // 49664 B

    const int tid   = threadIdx.x;
    const int lane  = tid & 63;
    const int w     = tid >> 6;
    const int col   = lane & 15;
    const int quad  = lane >> 4;
    const int mb    = blockIdx.x;
    const int split = blockIdx.y;
    const int m0    = mb * 256 + w * 64;
    const int nb0   = split * 256;

    // A fragments: 4 tiles x 3 planes x 2 ksteps (96 VGPRs)
    short8 af[4][3][2];
    #pragma unroll
    for (int t = 0; t < 4; ++t) {
        int pt = m0 + t * 16 + col;
        #pragma unroll
        for (int p = 0; p < 3; ++p)
            #pragma unroll
            for (int s = 0; s < 2; ++s) {
                int g = s * 4 + quad;
                af[t][p][s] = *(const short8*)(xS + ((size_t)(p * 8 + g) * 8192 + pt) * 8);
            }
    }

    float bestv[4][4];
    int   besti[4][4];
    #pragma unroll
    for (int t = 0; t < 4; ++t)
        #pragma unroll
        for (int r = 0; r < 4; ++r) {
            bestv[t][r] = __uint_as_float(0xFF800000u);  // -inf
            besti[t][r] = 0;
        }

    // async stage of one 64-code chunk: 24 segs x 1KB + e2 slice
    auto stage = [&](int k0, int buf) {
        unsigned short* dst = &sBuf[buf][0];
        #pragma unroll
        for (int i = 0; i < 6; ++i) {
            int f   = tid + i * 256;
            int seg = f >> 6;                // wave-uniform (tid,i aligned)
            int l   = f & 63;                // = lane
            cp16(cbS + ((size_t)seg * 8192 + k0 + l) * 8,
                 dst + seg * SEG_SHORTS + l * 8);
        }
        if (tid < 64)
            cp4(e2h + k0 + tid, (float*)(dst + 24 * SEG_SHORTS) + tid);
    };

    stage(nb0, 0);
    __syncthreads();                          // drain vmcnt -> chunk 0 ready

    for (int ch = 0; ch < 4; ++ch) {
        if (ch + 1 < 4) stage(nb0 + (ch + 1) * 64, (ch + 1) & 1);
        const unsigned short* bsrc = &sBuf[ch & 1][0];
        #pragma unroll
        for (int tl = 0; tl < 4; ++tl)
            computeTileLDS(af, bsrc, tl, quad, col,
                           nb0 + ch * 64 + tl * 16 + col, bestv, besti);
        __syncthreads();                      // reads done + next stage visible
    }

    // pack (key = -score, ascending) + cross-col reduce via LDS
    // (aliases sBuf: 256*17*8 = 34816 B <= 49664 B, after final barrier)
    unsigned long long* red = (unsigned long long*)&sBuf[0][0];
    #pragma unroll
    for (int t = 0; t < 4; ++t)
        #pragma unroll
        for (int r = 0; r < 4; ++r) {
            unsigned u = __float_as_uint(-bestv[t][r]);
            u = ((int)u < 0) ? ~u : (u | 0x80000000u);
            unsigned long long p = ((unsigned long long)u << 32) | (unsigned)besti[t][r];
            red[(w * 64 + t * 16 + quad * 4 + r) * 17 + col] = p;
        }
    __syncthreads();
    unsigned long long v = red[tid * 17];
    #pragma unroll
    for (int c = 1; c < 16; ++c) {
        unsigned long long q = red[tid * 17 + c];
        v = (q < v) ? q : v;
    }
    packedS[(size_t)split * N_PTS + mb * 256 + tid] = v;
}

// ============================================================
// Kernel C: gather. 128 blocks x 256; block owns 64 points.
// Wave 0 reduces the 32 split slots once per point, broadcasts
// idx via LDS + writes indices. All 4 waves then handle one
// 16-channel quarter each (fully coalesced x/out access).
// ============================================================
__global__ __launch_bounds__(256)
void vq_gather_kernel(const float* __restrict__ x,
                      const float* __restrict__ cb,
                      const unsigned long long* __restrict__ packedS,
                      float* __restrict__ out,
                      float* __restrict__ part)
{
    __shared__ int sidx[64];
    const int tid  = threadIdx.x;
    const int lane = tid & 63;
    const int qd   = tid >> 6;          // wave id = channel quarter
    const int n0   = blockIdx.x * 64;
    const int n    = n0 + lane;

    if (qd == 0) {
        unsigned long long v = packedS[n];
        #pragma unroll
        for (int s = 1; s < SPLITS; ++s) {
            unsigned long long q = packedS[(size_t)s * N_PTS + n];
            v = (q < v) ? q : v;
        }
        int idx = (int)(v & 0xFFFFFFFFull);
        sidx[lane] = idx;
        out[QOUT_N + 2 + n] = (float)idx;
    }
    __syncthreads();

    const int idx = sidx[lane];
    const int c0  = qd * 16;
    const int b   = n >> 10;
    const int hw  = n & 1023;
    const float* xb = x   + (size_t)b * (C_DIM * HWSZ) + hw;
    float*       ob = out + (size_t)b * (C_DIM * HWSZ) + hw;

    float s = 0.0f;
    #pragma unroll
    for (int c4 = 0; c4 < 4; ++c4) {
        float4 q = *(const float4*)(cb + (size_t)idx * C_DIM + c0 + c4 * 4);
        float qa[4] = {q.x, q.y, q.z, q.w};
        #pragma unroll
        for (int j = 0; j < 4; ++j) {
            int c = c0 + c4 * 4 + j;
            float xv = xb[c * HWSZ];
            float d  = qa[j] - xv;          // quant - x (reference rounding)
            s = fmaf(d, d, s);
            ob[c * HWSZ] = xv + d;          // straight-through: x + (q - x)
        }
    }

    #pragma unroll
    for (int off = 32; off > 0; off >>= 1) s += __shfl_down(s, off, 64);
    if (lane == 0) part[blockIdx.x * 4 + qd] = s;
}

// ============================================================
// Kernel D: final loss reduction (512 partials -> 2 scalars).
// ============================================================
__global__ __launch_bounds__(256)
void vq_final_kernel(const float* __restrict__ part, float* __restrict__ out)
{
    __shared__ float w[4];
    float s = part[threadIdx.x] + part[threadIdx.x + 256];
    #pragma unroll
    for (int off = 32; off > 0; off >>= 1) s += __shfl_down(s, off, 64);
    if ((threadIdx.x & 63) == 0) w[threadIdx.x >> 6] = s;
    __syncthreads();
    if (threadIdx.x == 0) {
        float m = (w[0] + w[1] + w[2] + w[3]) * (1.0f / (float)QOUT_N);
        out[QOUT_N]     = m;   // commitment_loss
        out[QOUT_N + 1] = m;   // codebook_loss
    }
}

extern "C" void kernel_launch(void* const* d_in, const int* in_sizes, int n_in,
                              void* d_out, int out_size, void* d_ws, size_t ws_size,
                              hipStream_t stream)
{
    const float* x  = (const float*)d_in[0];   // [8,64,32,32]
    const float* cb = (const float*)d_in[1];   // [8192,64]
    float* out = (float*)d_out;
    char*  ws  = (char*)d_ws;
    (void)ws_size;

    unsigned short* xS  = (unsigned short*)(ws + WS_XS);
    unsigned short* cbS = (unsigned short*)(ws + WS_CBS);
    float* e2h = (float*)(ws + WS_E2H);
    unsigned long long* packedS = (unsigned long long*)(ws + WS_PACK);
    float* part = (float*)(ws + WS_PART);

    vq_prep_kernel<<<96, 256, 0, stream>>>(x, cb, xS, cbS, e2h);
    vq_argmin_kernel<<<dim3(N_PTS / 256, SPLITS), 256, 0, stream>>>(xS, cbS, e2h, packedS);
    vq_gather_kernel<<<128, 256, 0, stream>>>(x, cb, packedS, out, part);
    vq_final_kernel<<<1, 256, 0, stream>>>(part, out);
}